// Round 8
// baseline (2572.610 us; speedup 1.0000x reference)
//
#include <hip/hip_runtime.h>
#include <math.h>
#include <stdint.h>

#define USER_NUM 50000
#define ITEM_NUM 100000
#define NN (USER_NUM + ITEM_NUM)
#define D 64
#define TAU_INV 2.0f   // 1/0.5
#define LMBD 0.0001f
#define NCITER 16      // ssl col-iterations per block: 128*16 = 2048 cols/chunk
#define NRG 64         // ssl rowgroups (4096 A-rows / 64)
#define T3 (3 * NN)
#define NBLK3 ((T3 + 255) / 256)

typedef __bf16 bf16x8 __attribute__((ext_vector_type(8)));
typedef float  f32x4  __attribute__((ext_vector_type(4)));

static __device__ __forceinline__ unsigned short f2bf(float x) {
    union { float f; unsigned u; } v; v.f = x;
    unsigned r = v.u + 0x7FFFu + ((v.u >> 16) & 1u);   // RNE
    return (unsigned short)(r >> 16);
}
static __device__ __forceinline__ float bf2f(unsigned short b) {
    union { unsigned u; float f; } v; v.u = ((unsigned)b) << 16;
    return v.f;
}

// ---------------- init: hb = bf16(normS[row]*emb); acc = fp32 emb
__global__ void init_kernel(const float* __restrict__ ue, const float* __restrict__ ie,
                            const float* __restrict__ normS,
                            unsigned short* __restrict__ hb, float* __restrict__ acc) {
    int i = blockIdx.x * 256 + threadIdx.x;
    if (i < NN * D) {
        float v = (i < USER_NUM * D) ? ue[i] : ie[i - USER_NUM * D];
        hb[i] = f2bf(v * normS[i >> 6]);
        acc[i] = v;
    }
}

// ---------------- fused histograms over 3 graphs: dst (CSR) + src (weights)
__global__ void deg3_kernel(const int* __restrict__ d0, const int* __restrict__ d1,
                            const int* __restrict__ d2,
                            const int* __restrict__ s0, const int* __restrict__ s1,
                            const int* __restrict__ s2,
                            int* __restrict__ degD3, int* __restrict__ degS3,
                            int E0, int E1, int E2) {
    int i = blockIdx.x * 256 + threadIdx.x;
    int d, s, off;
    if (i < E0) { d = d0[i]; s = s0[i]; off = 0; }
    else if (i < E0 + E1) { int j = i - E0; d = d1[j]; s = s1[j]; off = NN; }
    else if (i < E0 + E1 + E2) { int j = i - E0 - E1; d = d2[j]; s = s2[j]; off = 2 * NN; }
    else return;
    atomicAdd(&degD3[off + d], 1);
    atomicAdd(&degS3[off + s], 1);
}

// normS3[i] = (max(degS,1))^-0.5
__global__ void norms_kernel(const int* __restrict__ degS3, float* __restrict__ normS3) {
    int i = blockIdx.x * 256 + threadIdx.x;
    if (i < T3) {
        float d = (float)max(degS3[i], 1);
        normS3[i] = rsqrtf(d);
    }
}

__global__ void scan_reduce_kernel(const int* __restrict__ deg, int* __restrict__ bsum) {
    __shared__ int sd[256];
    int tid = threadIdx.x;
    int i = blockIdx.x * 256 + tid;
    sd[tid] = (i < T3) ? deg[i] : 0;
    __syncthreads();
    for (int o = 128; o; o >>= 1) { if (tid < o) sd[tid] += sd[tid + o]; __syncthreads(); }
    if (tid == 0) bsum[blockIdx.x] = sd[0];
}

// single-block scan of up to 2048 block-sums (2 per thread); writes total -> *totp
__global__ void scan_mid_kernel(int* __restrict__ bsum, int* __restrict__ totp, int nblk) {
    __shared__ int sd[1024];
    int tid = threadIdx.x;
    int v0 = (2 * tid < nblk) ? bsum[2 * tid] : 0;
    int v1 = (2 * tid + 1 < nblk) ? bsum[2 * tid + 1] : 0;
    sd[tid] = v0 + v1;
    __syncthreads();
    for (int o = 1; o < 1024; o <<= 1) {
        int t = (tid >= o) ? sd[tid - o] : 0;
        __syncthreads();
        sd[tid] += t;
        __syncthreads();
    }
    int base = tid ? sd[tid - 1] : 0;
    if (2 * tid < nblk) bsum[2 * tid] = base;
    if (2 * tid + 1 < nblk) bsum[2 * tid + 1] = base + v0;
    if (tid == 1023) totp[0] = sd[1023];
}

__global__ void scan_final_kernel(const int* __restrict__ deg, const int* __restrict__ bsum,
                                  int* __restrict__ rowptr, int* __restrict__ cursor) {
    __shared__ int sd[256];
    int tid = threadIdx.x;
    int i = blockIdx.x * 256 + tid;
    int v = (i < T3) ? deg[i] : 0;
    sd[tid] = v;
    __syncthreads();
    for (int o = 1; o < 256; o <<= 1) {
        int t = (tid >= o) ? sd[tid - o] : 0;
        __syncthreads();
        sd[tid] += t;
        __syncthreads();
    }
    if (i < T3) {
        int ex = sd[tid] - v + bsum[blockIdx.x];
        rowptr[i] = ex;
        cursor[i] = ex;
    }
}

// fill: perm[slot] = src only (4B)
__global__ void fill3_kernel(const int* __restrict__ s0, const int* __restrict__ d0,
                             const int* __restrict__ s1, const int* __restrict__ d1,
                             const int* __restrict__ s2, const int* __restrict__ d2,
                             int* __restrict__ cursor, int* __restrict__ perm,
                             int E0, int E1, int E2) {
    int i = blockIdx.x * 256 + threadIdx.x;
    int d, s;
    if (i < E0) { d = d0[i]; s = s0[i]; }
    else if (i < E0 + E1) { int j = i - E0; d = NN + d1[j]; s = s1[j]; }
    else if (i < E0 + E1 + E2) { int j = i - E0 - E1; d = 2 * NN + d2[j]; s = s2[j]; }
    else return;
    int p = atomicAdd(&cursor[d], 1);
    perm[p] = s;
}

// ---------------- fused gather + l2-norm + acc; hn (pre-scaled) optional
__global__ __launch_bounds__(256) void gather_norm_kernel(const unsigned short* __restrict__ hb,
        const int* __restrict__ rowptr, const int* __restrict__ perm,
        const float* __restrict__ normS,
        unsigned short* __restrict__ hn, float* __restrict__ acc) {
    int gid = blockIdx.x * 256 + threadIdx.x;
    int row = gid >> 6;
    int lane = gid & 63;
    if (row >= NN) return;
    int beg = rowptr[row];
    int end = rowptr[row + 1];
    float s = 0.f;
    int e = beg;
    for (; e + 8 <= end; e += 8) {
        int i0 = perm[e],     i1 = perm[e + 1], i2 = perm[e + 2], i3 = perm[e + 3];
        int i4 = perm[e + 4], i5 = perm[e + 5], i6 = perm[e + 6], i7 = perm[e + 7];
        float v0 = bf2f(hb[(size_t)i0 * D + lane]);
        float v1 = bf2f(hb[(size_t)i1 * D + lane]);
        float v2 = bf2f(hb[(size_t)i2 * D + lane]);
        float v3 = bf2f(hb[(size_t)i3 * D + lane]);
        float v4 = bf2f(hb[(size_t)i4 * D + lane]);
        float v5 = bf2f(hb[(size_t)i5 * D + lane]);
        float v6 = bf2f(hb[(size_t)i6 * D + lane]);
        float v7 = bf2f(hb[(size_t)i7 * D + lane]);
        s += ((v0 + v1) + (v2 + v3)) + ((v4 + v5) + (v6 + v7));
    }
    {
        int rem = end - e;
        int i0 = (rem > 0) ? perm[e] : 0;
        int i1 = (rem > 1) ? perm[e + 1] : 0;
        int i2 = (rem > 2) ? perm[e + 2] : 0;
        int i3 = (rem > 3) ? perm[e + 3] : 0;
        int i4 = (rem > 4) ? perm[e + 4] : 0;
        int i5 = (rem > 5) ? perm[e + 5] : 0;
        int i6 = (rem > 6) ? perm[e + 6] : 0;
        float v0 = (rem > 0) ? bf2f(hb[(size_t)i0 * D + lane]) : 0.f;
        float v1 = (rem > 1) ? bf2f(hb[(size_t)i1 * D + lane]) : 0.f;
        float v2 = (rem > 2) ? bf2f(hb[(size_t)i2 * D + lane]) : 0.f;
        float v3 = (rem > 3) ? bf2f(hb[(size_t)i3 * D + lane]) : 0.f;
        float v4 = (rem > 4) ? bf2f(hb[(size_t)i4 * D + lane]) : 0.f;
        float v5 = (rem > 5) ? bf2f(hb[(size_t)i5 * D + lane]) : 0.f;
        float v6 = (rem > 6) ? bf2f(hb[(size_t)i6 * D + lane]) : 0.f;
        s += ((v0 + v1) + (v2 + v3)) + ((v4 + v5) + v6);
    }
    float q = s * s;
    #pragma unroll
    for (int o = 32; o; o >>= 1) q += __shfl_xor(q, o);
    float y = s / fmaxf(sqrtf(q), 1e-12f);
    size_t idx = (size_t)row * D + lane;
    acc[idx] += y;
    if (hn) hn[idx] = f2bf(y * normS[row]);
}

// ---------------- row l2-normalize acc in place + write bf16 copy
__global__ void norm_rows_bf_kernel(float* __restrict__ h, unsigned short* __restrict__ hb) {
    int gid = blockIdx.x * 256 + threadIdx.x;
    int row = gid >> 6;
    int lane = gid & 63;
    if (row >= NN) return;
    size_t idx = (size_t)row * D + lane;
    float x = h[idx];
    float s = x * x;
    #pragma unroll
    for (int o = 32; o; o >>= 1) s += __shfl_xor(s, o);
    float y = x / fmaxf(sqrtf(s), 1e-12f);
    h[idx] = y;
    hb[idx] = f2bf(y);
}

// ---------------- BPR: wave per sample
__global__ void bpr_kernel(const float* __restrict__ acc, const int* __restrict__ uid,
                           const int* __restrict__ iid, const int* __restrict__ nid,
                           float* __restrict__ scal, int B) {
    int gid = blockIdx.x * 256 + threadIdx.x;
    int r = gid >> 6;
    int lane = gid & 63;
    if (r >= B) return;
    const float inv = 1.0f / 5.0f;  // MAIN_LAYERS+1
    float ue = acc[(size_t)uid[r] * D + lane] * inv;
    float pe = acc[(size_t)(USER_NUM + iid[r]) * D + lane] * inv;
    float ne = acc[(size_t)(USER_NUM + nid[r]) * D + lane] * inv;
    float pos = ue * pe, neg = ue * ne, reg = ue * ue + pe * pe + ne * ne;
    #pragma unroll
    for (int o = 32; o; o >>= 1) {
        pos += __shfl_xor(pos, o);
        neg += __shfl_xor(neg, o);
        reg += __shfl_xor(reg, o);
    }
    if (lane == 0) {
        float x = pos - neg;
        float ls = (x >= 0.f) ? (-log1pf(expf(-x))) : (x - log1pf(expf(x)));
        atomicAdd(&scal[0], -ls);
        atomicAdd(&scal[1], reg * 0.5f);
    }
}

// ---------------- extract sampled rows from acc, l2-normalize -> bf16
__global__ void extract_norm_kernel(const float* __restrict__ acc, const int* __restrict__ uid,
                                    const int* __restrict__ iid, unsigned short* __restrict__ ue1b,
                                    unsigned short* __restrict__ ie1b, int B) {
    int gid = blockIdx.x * 256 + threadIdx.x;
    int t = gid >> 6;
    int lane = gid & 63;
    if (t >= 2 * B) return;
    bool user = (t < B);
    int r = user ? t : (t - B);
    size_t srow = user ? (size_t)uid[r] * D : (size_t)(USER_NUM + iid[r]) * D;
    float x = acc[srow + lane];
    float s = x * x;
    #pragma unroll
    for (int o = 32; o; o >>= 1) s += __shfl_xor(s, o);
    float y = x / fmaxf(sqrtf(s), 1e-12f);
    (user ? ue1b : ie1b)[(size_t)r * D + lane] = f2bf(y);
}

// ---------------- big SSL via MFMA, XCD-locality grid
__global__ __launch_bounds__(256) void ssl_mfma_kernel(const unsigned short* __restrict__ Ab,
                                                       const unsigned short* __restrict__ Bb,
                                                       float* __restrict__ rowsum,
                                                       int M, int nc) {
    int bid = blockIdx.x;
    int xcd = bid & 7;
    int inner = bid >> 3;
    int rg = inner & (NRG - 1);
    int cgrp = inner >> 6;
    int colChunk = cgrp * 8 + xcd;
    if (colChunk >= nc) return;

    int wave = threadIdx.x >> 6;
    int lane = threadIdx.x & 63;
    int l15 = lane & 15;
    int lg  = lane >> 4;
    int rgbase = rg * 64;
    int chunkbase = colChunk * (128 * NCITER);

    bf16x8 afr[4][2];
    {
        const unsigned short* ab = Ab + (size_t)(rgbase + l15) * D + lg * 8;
        #pragma unroll
        for (int i = 0; i < 4; i++) {
            afr[i][0] = *(const bf16x8*)(ab + (size_t)i * 16 * D);
            afr[i][1] = *(const bf16x8*)(ab + (size_t)i * 16 * D + 32);
        }
    }

    float rowacc[4][4];
    #pragma unroll
    for (int i = 0; i < 4; i++)
        #pragma unroll
        for (int r = 0; r < 4; r++) rowacc[i][r] = 0.f;

    for (int it = 0; it < NCITER; it++) {
        int cb = chunkbase + it * 128 + wave * 32;
        bf16x8 bfr[2][2];
        bool val[2];
        #pragma unroll
        for (int cf = 0; cf < 2; cf++) {
            int col = cb + cf * 16 + l15;
            val[cf] = (col < M);
            int cc = val[cf] ? col : (M - 1);
            const unsigned short* bp = Bb + (size_t)cc * D + lg * 8;
            bfr[cf][0] = *(const bf16x8*)(bp);
            bfr[cf][1] = *(const bf16x8*)(bp + 32);
        }

        f32x4 acc[4][2];
        #pragma unroll
        for (int i = 0; i < 4; i++)
            #pragma unroll
            for (int cf = 0; cf < 2; cf++)
                acc[i][cf] = (f32x4){0.f, 0.f, 0.f, 0.f};

        #pragma unroll
        for (int i = 0; i < 4; i++) {
            #pragma unroll
            for (int cf = 0; cf < 2; cf++) {
                acc[i][cf] = __builtin_amdgcn_mfma_f32_16x16x32_bf16(afr[i][0], bfr[cf][0], acc[i][cf], 0, 0, 0);
                acc[i][cf] = __builtin_amdgcn_mfma_f32_16x16x32_bf16(afr[i][1], bfr[cf][1], acc[i][cf], 0, 0, 0);
            }
        }

        #pragma unroll
        for (int i = 0; i < 4; i++) {
            #pragma unroll
            for (int r = 0; r < 4; r++) {
                float e0 = val[0] ? __expf(TAU_INV * acc[i][0][r]) : 0.f;
                float e1 = val[1] ? __expf(TAU_INV * acc[i][1][r]) : 0.f;
                rowacc[i][r] += e0 + e1;
            }
        }
    }

    #pragma unroll
    for (int i = 0; i < 4; i++) {
        #pragma unroll
        for (int r = 0; r < 4; r++) {
            float s = rowacc[i][r];
            s += __shfl_xor(s, 1);
            s += __shfl_xor(s, 2);
            s += __shfl_xor(s, 4);
            s += __shfl_xor(s, 8);
            if (l15 == 0) atomicAdd(&rowsum[rgbase + i * 16 + lg * 4 + r], s);
        }
    }
}

// ---------------- SSL finalize
__global__ void ssl_fin_kernel(const unsigned short* __restrict__ ue1b,
                               const unsigned short* __restrict__ ie1b,
                               const float* __restrict__ A2, const int* __restrict__ uid,
                               const int* __restrict__ iid, const float* __restrict__ rsU,
                               const float* __restrict__ rsI, float* __restrict__ scal, int B) {
    int gid = blockIdx.x * 256 + threadIdx.x;
    int t = gid >> 6;
    int lane = gid & 63;
    if (t >= 2 * B) return;
    bool user = (t < B);
    int r = user ? t : (t - B);
    const unsigned short* a = (user ? ue1b : ie1b) + (size_t)r * D;
    size_t brow = user ? (size_t)uid[r] * D : (size_t)(USER_NUM + iid[r]) * D;
    float p = bf2f(a[lane]) * A2[brow + lane];
    #pragma unroll
    for (int o = 32; o; o >>= 1) p += __shfl_xor(p, o);
    if (lane == 0) {
        float contrib = logf((user ? rsU : rsI)[r]) - p * TAU_INV;
        atomicAdd(&scal[user ? 2 : 3], contrib);
    }
}

// ---------------- final scalar
__global__ void final_kernel(const float* __restrict__ scal, float* __restrict__ out, int B) {
    if (threadIdx.x == 0 && blockIdx.x == 0) {
        float invB = 1.0f / (float)B;
        float bpr_loss = scal[0] * invB + LMBD * scal[1] * invB;
        float ssl_loss = (scal[2] + scal[3]) * 0.1f;
        out[0] = bpr_loss + ssl_loss;
    }
}

extern "C" void kernel_launch(void* const* d_in, const int* in_sizes, int n_in,
                              void* d_out, int out_size, void* d_ws, size_t ws_size,
                              hipStream_t stream) {
    const float* user_emb = (const float*)d_in[0];
    const float* item_emb = (const float*)d_in[1];
    const int*   src  = (const int*)d_in[2];
    const int*   dst  = (const int*)d_in[3];
    const int*   src1 = (const int*)d_in[5];
    const int*   dst1 = (const int*)d_in[6];
    const int*   src2 = (const int*)d_in[8];
    const int*   dst2 = (const int*)d_in[9];
    const int* user_id = (const int*)d_in[11];
    const int* item_id = (const int*)d_in[12];
    const int* neg_id  = (const int*)d_in[13];
    int E0 = in_sizes[2];
    int E1 = in_sizes[5];
    int E2 = in_sizes[8];
    int B  = in_sizes[11];
    int ET = E0 + E1 + E2;

    size_t nd = (size_t)NN * D;
    float* acc = (float*)d_ws;                       // fp32 NN*D
    unsigned short* hAb = (unsigned short*)(acc + nd);
    unsigned short* hBb = hAb + nd;
    unsigned short* ue1b = hBb + nd;
    unsigned short* ie1b = ue1b + (size_t)B * D;
    float* rsU  = (float*)(ie1b + (size_t)B * D);
    float* rsI  = rsU + B;
    float* scal = rsI + B;                 // 8 floats
    int* degD3   = (int*)(scal + 8);       // 3*NN
    int* degS3   = degD3 + T3;             // 3*NN
    float* normS3 = (float*)(degS3 + T3);  // 3*NN
    int* rowptr3 = (int*)(normS3 + T3);    // 3*NN + 1
    int* cursor3 = rowptr3 + T3 + 1;       // 3*NN
    int* bsum3   = cursor3 + T3;           // up to 2048
    int* perm3   = bsum3 + 2048;           // ET ints
    unsigned short* bbuf = hAb;            // reuse after last propagation

    hipMemsetAsync(rsU, 0, (size_t)(2 * B + 8) * sizeof(float), stream);
    hipMemsetAsync(degD3, 0, (size_t)(2 * T3) * sizeof(int), stream);

    int gridElem = (NN * D + 255) / 256;
    int gridRows = (NN * 64 + 255) / 256;
    int gridE3 = (ET + 255) / 256;
    int gridT3 = (T3 + 255) / 256;

    // ---- fused CSR + norm build for all 3 graphs
    deg3_kernel<<<gridE3, 256, 0, stream>>>(dst, dst1, dst2, src, src1, src2,
                                            degD3, degS3, E0, E1, E2);
    norms_kernel<<<gridT3, 256, 0, stream>>>(degS3, normS3);
    scan_reduce_kernel<<<NBLK3, 256, 0, stream>>>(degD3, bsum3);
    scan_mid_kernel<<<1, 1024, 0, stream>>>(bsum3, rowptr3 + T3, NBLK3);
    scan_final_kernel<<<NBLK3, 256, 0, stream>>>(degD3, bsum3, rowptr3, cursor3);
    fill3_kernel<<<gridE3, 256, 0, stream>>>(src, dst, src1, dst1, src2, dst2,
                                             cursor3, perm3, E0, E1, E2);

    auto propagate = [&](int g, int layers) {
        const int* rp = rowptr3 + (size_t)g * NN;
        const float* ns = normS3 + (size_t)g * NN;
        init_kernel<<<gridElem, 256, 0, stream>>>(user_emb, item_emb, ns, hAb, acc);
        unsigned short* cur = hAb;
        unsigned short* nxt = hBb;
        for (int l = 0; l < layers; l++) {
            bool last = (l == layers - 1);
            gather_norm_kernel<<<gridRows, 256, 0, stream>>>(cur, rp, perm3, ns,
                                                             last ? (unsigned short*)nullptr : nxt,
                                                             acc);
            unsigned short* t = cur; cur = nxt; nxt = t;
        }
    };

    // main graph: 4 layers -> BPR
    propagate(0, 4);
    bpr_kernel<<<(B * 64) / 256, 256, 0, stream>>>(acc, user_id, item_id, neg_id, scal, B);

    // ssl graph 1: 3 layers -> bf16 normalized sampled rows
    propagate(1, 3);
    extract_norm_kernel<<<(2 * B * 64) / 256, 256, 0, stream>>>(acc, user_id, item_id, ue1b, ie1b, B);

    // ssl graph 2: 3 layers -> normalize acc in place + bf16 copy
    propagate(2, 3);
    norm_rows_bf_kernel<<<gridRows, 256, 0, stream>>>(acc, bbuf);

    // big SSL terms via MFMA (XCD-locality 1-D grid)
    {
        int ncU = (USER_NUM + 128 * NCITER - 1) / (128 * NCITER);
        int gu = 8 * NRG * ((ncU + 7) / 8);
        ssl_mfma_kernel<<<gu, 256, 0, stream>>>(ue1b, bbuf, rsU, USER_NUM, ncU);
        int ncI = (ITEM_NUM + 128 * NCITER - 1) / (128 * NCITER);
        int gi = 8 * NRG * ((ncI + 7) / 8);
        ssl_mfma_kernel<<<gi, 256, 0, stream>>>(ie1b, bbuf + (size_t)USER_NUM * D, rsI, ITEM_NUM, ncI);
    }

    ssl_fin_kernel<<<(2 * B * 64) / 256, 256, 0, stream>>>(ue1b, ie1b, acc, user_id, item_id,
                                                           rsU, rsI, scal, B);
    final_kernel<<<1, 64, 0, stream>>>(scal, (float*)d_out, B);
}

// Round 10
// 2537.294 us; speedup vs baseline: 1.0139x; 1.0139x over previous
//
#include <hip/hip_runtime.h>
#include <math.h>
#include <stdint.h>

#define USER_NUM 50000
#define ITEM_NUM 100000
#define NN (USER_NUM + ITEM_NUM)
#define D 64
#define TAU_INV 2.0f   // 1/0.5
#define LMBD 0.0001f
#define NCITER 16      // ssl col-iterations per block: 128*16 = 2048 cols/chunk
#define NRG 64         // ssl rowgroups (4096 A-rows / 64)
#define T3 (3 * NN)
#define NBLK3 ((T3 + 255) / 256)

typedef __bf16 bf16x8 __attribute__((ext_vector_type(8)));
typedef float  f32x4  __attribute__((ext_vector_type(4)));

static __device__ __forceinline__ unsigned short f2bf(float x) {
    union { float f; unsigned u; } v; v.f = x;
    unsigned r = v.u + 0x7FFFu + ((v.u >> 16) & 1u);   // RNE
    return (unsigned short)(r >> 16);
}
static __device__ __forceinline__ float bf2f(unsigned short b) {
    union { unsigned u; float f; } v; v.u = ((unsigned)b) << 16;
    return v.f;
}

// ---------------- init: hb = bf16(normS[row]*emb); acc = fp32 emb
__global__ void init_kernel(const float* __restrict__ ue, const float* __restrict__ ie,
                            const float* __restrict__ normS,
                            unsigned short* __restrict__ hb, float* __restrict__ acc) {
    int i = blockIdx.x * 256 + threadIdx.x;
    if (i < NN * D) {
        float v = (i < USER_NUM * D) ? ue[i] : ie[i - USER_NUM * D];
        hb[i] = f2bf(v * normS[i >> 6]);
        acc[i] = v;
    }
}

// ---------------- fused histograms over 3 graphs: dst (CSR) + src (weights)
__global__ void deg3_kernel(const int* __restrict__ d0, const int* __restrict__ d1,
                            const int* __restrict__ d2,
                            const int* __restrict__ s0, const int* __restrict__ s1,
                            const int* __restrict__ s2,
                            int* __restrict__ degD3, int* __restrict__ degS3,
                            int E0, int E1, int E2) {
    int i = blockIdx.x * 256 + threadIdx.x;
    int d, s, off;
    if (i < E0) { d = d0[i]; s = s0[i]; off = 0; }
    else if (i < E0 + E1) { int j = i - E0; d = d1[j]; s = s1[j]; off = NN; }
    else if (i < E0 + E1 + E2) { int j = i - E0 - E1; d = d2[j]; s = s2[j]; off = 2 * NN; }
    else return;
    atomicAdd(&degD3[off + d], 1);
    atomicAdd(&degS3[off + s], 1);
}

// normS3[i] = (max(degS,1))^-0.5
__global__ void norms_kernel(const int* __restrict__ degS3, float* __restrict__ normS3) {
    int i = blockIdx.x * 256 + threadIdx.x;
    if (i < T3) {
        float d = (float)max(degS3[i], 1);
        normS3[i] = rsqrtf(d);
    }
}

__global__ void scan_reduce_kernel(const int* __restrict__ deg, int* __restrict__ bsum) {
    __shared__ int sd[256];
    int tid = threadIdx.x;
    int i = blockIdx.x * 256 + tid;
    sd[tid] = (i < T3) ? deg[i] : 0;
    __syncthreads();
    for (int o = 128; o; o >>= 1) { if (tid < o) sd[tid] += sd[tid + o]; __syncthreads(); }
    if (tid == 0) bsum[blockIdx.x] = sd[0];
}

// single-block scan of up to 2048 block-sums (2 per thread); writes total -> *totp
__global__ void scan_mid_kernel(int* __restrict__ bsum, int* __restrict__ totp, int nblk) {
    __shared__ int sd[1024];
    int tid = threadIdx.x;
    int v0 = (2 * tid < nblk) ? bsum[2 * tid] : 0;
    int v1 = (2 * tid + 1 < nblk) ? bsum[2 * tid + 1] : 0;
    sd[tid] = v0 + v1;
    __syncthreads();
    for (int o = 1; o < 1024; o <<= 1) {
        int t = (tid >= o) ? sd[tid - o] : 0;
        __syncthreads();
        sd[tid] += t;
        __syncthreads();
    }
    int base = tid ? sd[tid - 1] : 0;
    if (2 * tid < nblk) bsum[2 * tid] = base;
    if (2 * tid + 1 < nblk) bsum[2 * tid + 1] = base + v0;
    if (tid == 1023) totp[0] = sd[1023];
}

__global__ void scan_final_kernel(const int* __restrict__ deg, const int* __restrict__ bsum,
                                  int* __restrict__ rowptr, int* __restrict__ cursor) {
    __shared__ int sd[256];
    int tid = threadIdx.x;
    int i = blockIdx.x * 256 + tid;
    int v = (i < T3) ? deg[i] : 0;
    sd[tid] = v;
    __syncthreads();
    for (int o = 1; o < 256; o <<= 1) {
        int t = (tid >= o) ? sd[tid - o] : 0;
        __syncthreads();
        sd[tid] += t;
        __syncthreads();
    }
    if (i < T3) {
        int ex = sd[tid] - v + bsum[blockIdx.x];
        rowptr[i] = ex;
        cursor[i] = ex;
    }
}

// fill: perm[slot] = src only (4B)
__global__ void fill3_kernel(const int* __restrict__ s0, const int* __restrict__ d0,
                             const int* __restrict__ s1, const int* __restrict__ d1,
                             const int* __restrict__ s2, const int* __restrict__ d2,
                             int* __restrict__ cursor, int* __restrict__ perm,
                             int E0, int E1, int E2) {
    int i = blockIdx.x * 256 + threadIdx.x;
    int d, s;
    if (i < E0) { d = d0[i]; s = s0[i]; }
    else if (i < E0 + E1) { int j = i - E0; d = NN + d1[j]; s = s1[j]; }
    else if (i < E0 + E1 + E2) { int j = i - E0 - E1; d = 2 * NN + d2[j]; s = s2[j]; }
    else return;
    int p = atomicAdd(&cursor[d], 1);
    perm[p] = s;
}

// ---------------- fused gather + l2-norm + acc; hn (pre-scaled) optional
__global__ __launch_bounds__(256) void gather_norm_kernel(const unsigned short* __restrict__ hb,
        const int* __restrict__ rowptr, const int* __restrict__ perm,
        const float* __restrict__ normS,
        unsigned short* __restrict__ hn, float* __restrict__ acc) {
    int gid = blockIdx.x * 256 + threadIdx.x;
    int row = gid >> 6;
    int lane = gid & 63;
    if (row >= NN) return;
    int beg = rowptr[row];
    int end = rowptr[row + 1];
    float s = 0.f;
    int e = beg;
    for (; e + 8 <= end; e += 8) {
        int i0 = perm[e],     i1 = perm[e + 1], i2 = perm[e + 2], i3 = perm[e + 3];
        int i4 = perm[e + 4], i5 = perm[e + 5], i6 = perm[e + 6], i7 = perm[e + 7];
        float v0 = bf2f(hb[(size_t)i0 * D + lane]);
        float v1 = bf2f(hb[(size_t)i1 * D + lane]);
        float v2 = bf2f(hb[(size_t)i2 * D + lane]);
        float v3 = bf2f(hb[(size_t)i3 * D + lane]);
        float v4 = bf2f(hb[(size_t)i4 * D + lane]);
        float v5 = bf2f(hb[(size_t)i5 * D + lane]);
        float v6 = bf2f(hb[(size_t)i6 * D + lane]);
        float v7 = bf2f(hb[(size_t)i7 * D + lane]);
        s += ((v0 + v1) + (v2 + v3)) + ((v4 + v5) + (v6 + v7));
    }
    for (; e < end; e++) {
        s += bf2f(hb[(size_t)perm[e] * D + lane]);
    }
    float q = s * s;
    #pragma unroll
    for (int o = 32; o; o >>= 1) q += __shfl_xor(q, o);
    float y = s / fmaxf(sqrtf(q), 1e-12f);
    size_t idx = (size_t)row * D + lane;
    acc[idx] += y;
    if (hn) hn[idx] = f2bf(y * normS[row]);
}

// ---------------- row l2-normalize acc in place + write bf16 copy
__global__ void norm_rows_bf_kernel(float* __restrict__ h, unsigned short* __restrict__ hb) {
    int gid = blockIdx.x * 256 + threadIdx.x;
    int row = gid >> 6;
    int lane = gid & 63;
    if (row >= NN) return;
    size_t idx = (size_t)row * D + lane;
    float x = h[idx];
    float s = x * x;
    #pragma unroll
    for (int o = 32; o; o >>= 1) s += __shfl_xor(s, o);
    float y = x / fmaxf(sqrtf(s), 1e-12f);
    h[idx] = y;
    hb[idx] = f2bf(y);
}

// ---------------- BPR: wave per sample
__global__ void bpr_kernel(const float* __restrict__ acc, const int* __restrict__ uid,
                           const int* __restrict__ iid, const int* __restrict__ nid,
                           float* __restrict__ scal, int B) {
    int gid = blockIdx.x * 256 + threadIdx.x;
    int r = gid >> 6;
    int lane = gid & 63;
    if (r >= B) return;
    const float inv = 1.0f / 5.0f;  // MAIN_LAYERS+1
    float ue = acc[(size_t)uid[r] * D + lane] * inv;
    float pe = acc[(size_t)(USER_NUM + iid[r]) * D + lane] * inv;
    float ne = acc[(size_t)(USER_NUM + nid[r]) * D + lane] * inv;
    float pos = ue * pe, neg = ue * ne, reg = ue * ue + pe * pe + ne * ne;
    #pragma unroll
    for (int o = 32; o; o >>= 1) {
        pos += __shfl_xor(pos, o);
        neg += __shfl_xor(neg, o);
        reg += __shfl_xor(reg, o);
    }
    if (lane == 0) {
        float x = pos - neg;
        float ls = (x >= 0.f) ? (-log1pf(expf(-x))) : (x - log1pf(expf(x)));
        atomicAdd(&scal[0], -ls);
        atomicAdd(&scal[1], reg * 0.5f);
    }
}

// ---------------- extract sampled rows from acc, l2-normalize -> bf16
__global__ void extract_norm_kernel(const float* __restrict__ acc, const int* __restrict__ uid,
                                    const int* __restrict__ iid, unsigned short* __restrict__ ue1b,
                                    unsigned short* __restrict__ ie1b, int B) {
    int gid = blockIdx.x * 256 + threadIdx.x;
    int t = gid >> 6;
    int lane = gid & 63;
    if (t >= 2 * B) return;
    bool user = (t < B);
    int r = user ? t : (t - B);
    size_t srow = user ? (size_t)uid[r] * D : (size_t)(USER_NUM + iid[r]) * D;
    float x = acc[srow + lane];
    float s = x * x;
    #pragma unroll
    for (int o = 32; o; o >>= 1) s += __shfl_xor(s, o);
    float y = x / fmaxf(sqrtf(s), 1e-12f);
    (user ? ue1b : ie1b)[(size_t)r * D + lane] = f2bf(y);
}

// ---------------- big SSL via MFMA, XCD-locality grid
__global__ __launch_bounds__(256) void ssl_mfma_kernel(const unsigned short* __restrict__ Ab,
                                                       const unsigned short* __restrict__ Bb,
                                                       float* __restrict__ rowsum,
                                                       int M, int nc) {
    int bid = blockIdx.x;
    int xcd = bid & 7;
    int inner = bid >> 3;
    int rg = inner & (NRG - 1);
    int cgrp = inner >> 6;
    int colChunk = cgrp * 8 + xcd;
    if (colChunk >= nc) return;

    int wave = threadIdx.x >> 6;
    int lane = threadIdx.x & 63;
    int l15 = lane & 15;
    int lg  = lane >> 4;
    int rgbase = rg * 64;
    int chunkbase = colChunk * (128 * NCITER);

    bf16x8 afr[4][2];
    {
        const unsigned short* ab = Ab + (size_t)(rgbase + l15) * D + lg * 8;
        #pragma unroll
        for (int i = 0; i < 4; i++) {
            afr[i][0] = *(const bf16x8*)(ab + (size_t)i * 16 * D);
            afr[i][1] = *(const bf16x8*)(ab + (size_t)i * 16 * D + 32);
        }
    }

    float rowacc[4][4];
    #pragma unroll
    for (int i = 0; i < 4; i++)
        #pragma unroll
        for (int r = 0; r < 4; r++) rowacc[i][r] = 0.f;

    for (int it = 0; it < NCITER; it++) {
        int cb = chunkbase + it * 128 + wave * 32;
        bf16x8 bfr[2][2];
        bool val[2];
        #pragma unroll
        for (int cf = 0; cf < 2; cf++) {
            int col = cb + cf * 16 + l15;
            val[cf] = (col < M);
            int cc = val[cf] ? col : (M - 1);
            const unsigned short* bp = Bb + (size_t)cc * D + lg * 8;
            bfr[cf][0] = *(const bf16x8*)(bp);
            bfr[cf][1] = *(const bf16x8*)(bp + 32);
        }

        f32x4 acc[4][2];
        #pragma unroll
        for (int i = 0; i < 4; i++)
            #pragma unroll
            for (int cf = 0; cf < 2; cf++)
                acc[i][cf] = (f32x4){0.f, 0.f, 0.f, 0.f};

        #pragma unroll
        for (int i = 0; i < 4; i++) {
            #pragma unroll
            for (int cf = 0; cf < 2; cf++) {
                acc[i][cf] = __builtin_amdgcn_mfma_f32_16x16x32_bf16(afr[i][0], bfr[cf][0], acc[i][cf], 0, 0, 0);
                acc[i][cf] = __builtin_amdgcn_mfma_f32_16x16x32_bf16(afr[i][1], bfr[cf][1], acc[i][cf], 0, 0, 0);
            }
        }

        #pragma unroll
        for (int i = 0; i < 4; i++) {
            #pragma unroll
            for (int r = 0; r < 4; r++) {
                float e0 = val[0] ? __expf(TAU_INV * acc[i][0][r]) : 0.f;
                float e1 = val[1] ? __expf(TAU_INV * acc[i][1][r]) : 0.f;
                rowacc[i][r] += e0 + e1;
            }
        }
    }

    #pragma unroll
    for (int i = 0; i < 4; i++) {
        #pragma unroll
        for (int r = 0; r < 4; r++) {
            float s = rowacc[i][r];
            s += __shfl_xor(s, 1);
            s += __shfl_xor(s, 2);
            s += __shfl_xor(s, 4);
            s += __shfl_xor(s, 8);
            if (l15 == 0) atomicAdd(&rowsum[rgbase + i * 16 + lg * 4 + r], s);
        }
    }
}

// ---------------- SSL finalize
__global__ void ssl_fin_kernel(const unsigned short* __restrict__ ue1b,
                               const unsigned short* __restrict__ ie1b,
                               const float* __restrict__ A2, const int* __restrict__ uid,
                               const int* __restrict__ iid, const float* __restrict__ rsU,
                               const float* __restrict__ rsI, float* __restrict__ scal, int B) {
    int gid = blockIdx.x * 256 + threadIdx.x;
    int t = gid >> 6;
    int lane = gid & 63;
    if (t >= 2 * B) return;
    bool user = (t < B);
    int r = user ? t : (t - B);
    const unsigned short* a = (user ? ue1b : ie1b) + (size_t)r * D;
    size_t brow = user ? (size_t)uid[r] * D : (size_t)(USER_NUM + iid[r]) * D;
    float p = bf2f(a[lane]) * A2[brow + lane];
    #pragma unroll
    for (int o = 32; o; o >>= 1) p += __shfl_xor(p, o);
    if (lane == 0) {
        float contrib = logf((user ? rsU : rsI)[r]) - p * TAU_INV;
        atomicAdd(&scal[user ? 2 : 3], contrib);
    }
}

// ---------------- final scalar
__global__ void final_kernel(const float* __restrict__ scal, float* __restrict__ out, int B) {
    if (threadIdx.x == 0 && blockIdx.x == 0) {
        float invB = 1.0f / (float)B;
        float bpr_loss = scal[0] * invB + LMBD * scal[1] * invB;
        float ssl_loss = (scal[2] + scal[3]) * 0.1f;
        out[0] = bpr_loss + ssl_loss;
    }
}

extern "C" void kernel_launch(void* const* d_in, const int* in_sizes, int n_in,
                              void* d_out, int out_size, void* d_ws, size_t ws_size,
                              hipStream_t stream) {
    const float* user_emb = (const float*)d_in[0];
    const float* item_emb = (const float*)d_in[1];
    const int*   src  = (const int*)d_in[2];
    const int*   dst  = (const int*)d_in[3];
    const int*   src1 = (const int*)d_in[5];
    const int*   dst1 = (const int*)d_in[6];
    const int*   src2 = (const int*)d_in[8];
    const int*   dst2 = (const int*)d_in[9];
    const int* user_id = (const int*)d_in[11];
    const int* item_id = (const int*)d_in[12];
    const int* neg_id  = (const int*)d_in[13];
    int E0 = in_sizes[2];
    int E1 = in_sizes[5];
    int E2 = in_sizes[8];
    int B  = in_sizes[11];
    int ET = E0 + E1 + E2;

    size_t nd = (size_t)NN * D;
    float* acc = (float*)d_ws;                       // fp32 NN*D
    unsigned short* hAb = (unsigned short*)(acc + nd);
    unsigned short* hBb = hAb + nd;
    unsigned short* ue1b = hBb + nd;
    unsigned short* ie1b = ue1b + (size_t)B * D;
    float* rsU  = (float*)(ie1b + (size_t)B * D);
    float* rsI  = rsU + B;
    float* scal = rsI + B;                 // 8 floats
    int* degD3   = (int*)(scal + 8);       // 3*NN
    int* degS3   = degD3 + T3;             // 3*NN
    float* normS3 = (float*)(degS3 + T3);  // 3*NN
    int* rowptr3 = (int*)(normS3 + T3);    // 3*NN + 1
    int* cursor3 = rowptr3 + T3 + 1;       // 3*NN
    int* bsum3   = cursor3 + T3;           // up to 2048
    int* perm3   = bsum3 + 2048;           // ET ints
    unsigned short* bbuf = hAb;            // reuse after last propagation

    hipMemsetAsync(rsU, 0, (size_t)(2 * B + 8) * sizeof(float), stream);
    hipMemsetAsync(degD3, 0, (size_t)(2 * T3) * sizeof(int), stream);

    int gridElem = (NN * D + 255) / 256;
    int gridRows = (NN * 64 + 255) / 256;
    int gridE3 = (ET + 255) / 256;
    int gridT3 = (T3 + 255) / 256;

    // ---- fused CSR + norm build for all 3 graphs
    deg3_kernel<<<gridE3, 256, 0, stream>>>(dst, dst1, dst2, src, src1, src2,
                                            degD3, degS3, E0, E1, E2);
    norms_kernel<<<gridT3, 256, 0, stream>>>(degS3, normS3);
    scan_reduce_kernel<<<NBLK3, 256, 0, stream>>>(degD3, bsum3);
    scan_mid_kernel<<<1, 1024, 0, stream>>>(bsum3, rowptr3 + T3, NBLK3);
    scan_final_kernel<<<NBLK3, 256, 0, stream>>>(degD3, bsum3, rowptr3, cursor3);
    fill3_kernel<<<gridE3, 256, 0, stream>>>(src, dst, src1, dst1, src2, dst2,
                                             cursor3, perm3, E0, E1, E2);

    auto propagate = [&](int g, int layers) {
        const int* rp = rowptr3 + (size_t)g * NN;
        const float* ns = normS3 + (size_t)g * NN;
        init_kernel<<<gridElem, 256, 0, stream>>>(user_emb, item_emb, ns, hAb, acc);
        unsigned short* cur = hAb;
        unsigned short* nxt = hBb;
        for (int l = 0; l < layers; l++) {
            bool last = (l == layers - 1);
            gather_norm_kernel<<<gridRows, 256, 0, stream>>>(cur, rp, perm3, ns,
                                                             last ? (unsigned short*)nullptr : nxt,
                                                             acc);
            unsigned short* t = cur; cur = nxt; nxt = t;
        }
    };

    // main graph: 4 layers -> BPR
    propagate(0, 4);
    bpr_kernel<<<(B * 64) / 256, 256, 0, stream>>>(acc, user_id, item_id, neg_id, scal, B);

    // ssl graph 1: 3 layers -> bf16 normalized sampled rows
    propagate(1, 3);
    extract_norm_kernel<<<(2 * B * 64) / 256, 256, 0, stream>>>(acc, user_id, item_id, ue1b, ie1b, B);

    // ssl graph 2: 3 layers -> normalize acc in place + bf16 copy
    propagate(2, 3);
    norm_rows_bf_kernel<<<gridRows, 256, 0, stream>>>(acc, bbuf);

    // big SSL terms via MFMA (XCD-locality 1-D grid)
    {
        int ncU = (USER_NUM + 128 * NCITER - 1) / (128 * NCITER);
        int gu = 8 * NRG * ((ncU + 7) / 8);
        ssl_mfma_kernel<<<gu, 256, 0, stream>>>(ue1b, bbuf, rsU, USER_NUM, ncU);
        int ncI = (ITEM_NUM + 128 * NCITER - 1) / (128 * NCITER);
        int gi = 8 * NRG * ((ncI + 7) / 8);
        ssl_mfma_kernel<<<gi, 256, 0, stream>>>(ie1b, bbuf + (size_t)USER_NUM * D, rsI, ITEM_NUM, ncI);
    }

    ssl_fin_kernel<<<(2 * B * 64) / 256, 256, 0, stream>>>(ue1b, ie1b, acc, user_id, item_id,
                                                           rsU, rsI, scal, B);
    final_kernel<<<1, 64, 0, stream>>>(scal, (float*)d_out, B);
}

// Round 11
// 2000.092 us; speedup vs baseline: 1.2862x; 1.2686x over previous
//
#include <hip/hip_runtime.h>
#include <math.h>
#include <stdint.h>

#define USER_NUM 50000
#define ITEM_NUM 100000
#define NN (USER_NUM + ITEM_NUM)
#define D 64
#define TAU_INV 2.0f   // 1/0.5
#define LMBD 0.0001f
#define NCITER 16      // ssl col-iterations per block: 128*16 = 2048 cols/chunk
#define NRG 64         // ssl rowgroups (4096 A-rows / 64)
#define T3 (3 * NN)
#define NBLK3 ((T3 + 255) / 256)
#define EPB 8192       // edges per block for pinned CSR-build kernels
#define RR (T3 / 8)    // rows per XCD range (450000 divisible by 8)

typedef __bf16 bf16x8 __attribute__((ext_vector_type(8)));
typedef float  f32x4  __attribute__((ext_vector_type(4)));

static __device__ __forceinline__ unsigned short f2bf(float x) {
    union { float f; unsigned u; } v; v.f = x;
    unsigned r = v.u + 0x7FFFu + ((v.u >> 16) & 1u);   // RNE
    return (unsigned short)(r >> 16);
}
static __device__ __forceinline__ float bf2f(unsigned short b) {
    union { unsigned u; float f; } v; v.u = ((unsigned)b) << 16;
    return v.f;
}

// ---------------- init: h0 = bf16(concat(user,item))  (graph-independent)
__global__ void init_kernel(const float* __restrict__ ue, const float* __restrict__ ie,
                            unsigned short* __restrict__ h0) {
    int i = blockIdx.x * 256 + threadIdx.x;
    if (i < NN * D) {
        float v = (i < USER_NUM * D) ? ue[i] : ie[i - USER_NUM * D];
        h0[i] = f2bf(v);
    }
}

// ---------------- XCD-pinned dst histogram over 3 graphs
// blockIdx = chunk*8 + xcd; block reads its chunk's dsts, keeps rows in its 1/8 range.
__global__ __launch_bounds__(256) void deg3p_kernel(const int* __restrict__ d0,
        const int* __restrict__ d1, const int* __restrict__ d2,
        int* __restrict__ degD3, int E0, int E1, int E2, int ET) {
    int xcd = blockIdx.x & 7;
    int chunk = blockIdx.x >> 3;
    int base = chunk * EPB;
    int lo = xcd * RR, hi = lo + RR;
    for (int k = threadIdx.x; k < EPB; k += 256) {
        int i = base + k;
        if (i >= ET) break;
        int g;
        if (i < E0) g = d0[i];
        else if (i < E0 + E1) g = NN + d1[i - E0];
        else g = 2 * NN + d2[i - E0 - E1];
        if (g >= lo && g < hi) atomicAdd(&degD3[g], 1);
    }
}

__global__ void scan_reduce_kernel(const int* __restrict__ deg, int* __restrict__ bsum) {
    __shared__ int sd[256];
    int tid = threadIdx.x;
    int i = blockIdx.x * 256 + tid;
    sd[tid] = (i < T3) ? deg[i] : 0;
    __syncthreads();
    for (int o = 128; o; o >>= 1) { if (tid < o) sd[tid] += sd[tid + o]; __syncthreads(); }
    if (tid == 0) bsum[blockIdx.x] = sd[0];
}

// single-block scan of up to 2048 block-sums (2 per thread); writes total -> *totp
__global__ void scan_mid_kernel(int* __restrict__ bsum, int* __restrict__ totp, int nblk) {
    __shared__ int sd[1024];
    int tid = threadIdx.x;
    int v0 = (2 * tid < nblk) ? bsum[2 * tid] : 0;
    int v1 = (2 * tid + 1 < nblk) ? bsum[2 * tid + 1] : 0;
    sd[tid] = v0 + v1;
    __syncthreads();
    for (int o = 1; o < 1024; o <<= 1) {
        int t = (tid >= o) ? sd[tid - o] : 0;
        __syncthreads();
        sd[tid] += t;
        __syncthreads();
    }
    int base = tid ? sd[tid - 1] : 0;
    if (2 * tid < nblk) bsum[2 * tid] = base;
    if (2 * tid + 1 < nblk) bsum[2 * tid + 1] = base + v0;
    if (tid == 1023) totp[0] = sd[1023];
}

__global__ void scan_final_kernel(const int* __restrict__ deg, const int* __restrict__ bsum,
                                  int* __restrict__ rowptr, int* __restrict__ cursor) {
    __shared__ int sd[256];
    int tid = threadIdx.x;
    int i = blockIdx.x * 256 + tid;
    int v = (i < T3) ? deg[i] : 0;
    sd[tid] = v;
    __syncthreads();
    for (int o = 1; o < 256; o <<= 1) {
        int t = (tid >= o) ? sd[tid - o] : 0;
        __syncthreads();
        sd[tid] += t;
        __syncthreads();
    }
    if (i < T3) {
        int ex = sd[tid] - v + bsum[blockIdx.x];
        rowptr[i] = ex;
        cursor[i] = ex;
    }
}

// ---------------- XCD-pinned fill: perm[slot] = (src, w) grouped by dst
__global__ __launch_bounds__(256) void fill3p_kernel(
        const int* __restrict__ s0, const int* __restrict__ d0, const float* __restrict__ w0,
        const int* __restrict__ s1, const int* __restrict__ d1, const float* __restrict__ w1,
        const int* __restrict__ s2, const int* __restrict__ d2, const float* __restrict__ w2,
        int* __restrict__ cursor, int2* __restrict__ perm,
        int E0, int E1, int E2, int ET) {
    int xcd = blockIdx.x & 7;
    int chunk = blockIdx.x >> 3;
    int base = chunk * EPB;
    int lo = xcd * RR, hi = lo + RR;
    for (int k = threadIdx.x; k < EPB; k += 256) {
        int i = base + k;
        if (i >= ET) break;
        int g, s; float w;
        if (i < E0) {
            g = d0[i];
            if (g < lo || g >= hi) continue;
            s = s0[i]; w = w0[i];
        } else if (i < E0 + E1) {
            int j = i - E0;
            g = NN + d1[j];
            if (g < lo || g >= hi) continue;
            s = s1[j]; w = w1[j];
        } else {
            int j = i - E0 - E1;
            g = 2 * NN + d2[j];
            if (g < lo || g >= hi) continue;
            s = s2[j]; w = w2[j];
        }
        int p = atomicAdd(&cursor[g], 1);
        perm[p] = make_int2(s, __float_as_int(w));
    }
}

// ---------------- gather + l2-norm: one wave per dst row (no acc)
__global__ __launch_bounds__(256) void gather_kernel(const unsigned short* __restrict__ hb,
        const int* __restrict__ rowptr, const int2* __restrict__ perm,
        unsigned short* __restrict__ hn) {
    int gid = blockIdx.x * 256 + threadIdx.x;
    int row = gid >> 6;
    int lane = gid & 63;
    if (row >= NN) return;
    int beg = rowptr[row];
    int end = rowptr[row + 1];
    float s = 0.f;
    int e = beg;
    for (; e + 4 <= end; e += 4) {
        int2 p0 = perm[e];
        int2 p1 = perm[e + 1];
        int2 p2 = perm[e + 2];
        int2 p3 = perm[e + 3];
        float v0 = bf2f(hb[(size_t)p0.x * D + lane]);
        float v1 = bf2f(hb[(size_t)p1.x * D + lane]);
        float v2 = bf2f(hb[(size_t)p2.x * D + lane]);
        float v3 = bf2f(hb[(size_t)p3.x * D + lane]);
        s += v0 * __int_as_float(p0.y) + v1 * __int_as_float(p1.y)
           + v2 * __int_as_float(p2.y) + v3 * __int_as_float(p3.y);
    }
    for (; e < end; e++) {
        int2 p0 = perm[e];
        s += bf2f(hb[(size_t)p0.x * D + lane]) * __int_as_float(p0.y);
    }
    float q = s * s;
    #pragma unroll
    for (int o = 32; o; o >>= 1) q += __shfl_xor(q, o);
    float y = s / fmaxf(sqrtf(q), 1e-12f);
    hn[(size_t)row * D + lane] = f2bf(y);
}

// helper: raw embedding value at global row (fp32)
static __device__ __forceinline__ float emb_at(const float* ue, const float* ie,
                                               int grow, int lane) {
    return (grow < USER_NUM) ? ue[(size_t)grow * D + lane]
                             : ie[(size_t)(grow - USER_NUM) * D + lane];
}

// ---------------- BPR on-the-fly sum of 5 layers: wave per sample
__global__ void bpr_kernel(const float* __restrict__ ue_, const float* __restrict__ ie_,
                           const unsigned short* __restrict__ h1, const unsigned short* __restrict__ h2,
                           const unsigned short* __restrict__ h3, const unsigned short* __restrict__ h4,
                           const int* __restrict__ uid, const int* __restrict__ iid,
                           const int* __restrict__ nid, float* __restrict__ scal, int B) {
    int gid = blockIdx.x * 256 + threadIdx.x;
    int r = gid >> 6;
    int lane = gid & 63;
    if (r >= B) return;
    int g0 = uid[r], g1 = USER_NUM + iid[r], g2 = USER_NUM + nid[r];
    size_t i0 = (size_t)g0 * D + lane, i1 = (size_t)g1 * D + lane, i2 = (size_t)g2 * D + lane;
    const float inv = 0.2f;  // 1/5
    float ue = (emb_at(ue_, ie_, g0, lane) + bf2f(h1[i0]) + bf2f(h2[i0]) + bf2f(h3[i0]) + bf2f(h4[i0])) * inv;
    float pe = (emb_at(ue_, ie_, g1, lane) + bf2f(h1[i1]) + bf2f(h2[i1]) + bf2f(h3[i1]) + bf2f(h4[i1])) * inv;
    float ne = (emb_at(ue_, ie_, g2, lane) + bf2f(h1[i2]) + bf2f(h2[i2]) + bf2f(h3[i2]) + bf2f(h4[i2])) * inv;
    float pos = ue * pe, neg = ue * ne, reg = ue * ue + pe * pe + ne * ne;
    #pragma unroll
    for (int o = 32; o; o >>= 1) {
        pos += __shfl_xor(pos, o);
        neg += __shfl_xor(neg, o);
        reg += __shfl_xor(reg, o);
    }
    if (lane == 0) {
        float x = pos - neg;
        float ls = (x >= 0.f) ? (-log1pf(expf(-x))) : (x - log1pf(expf(x)));
        atomicAdd(&scal[0], -ls);
        atomicAdd(&scal[1], reg * 0.5f);
    }
}

// ---------------- extract sampled rows (sum of 4 layers), l2-normalize -> bf16
__global__ void extract_norm_kernel(const float* __restrict__ ue_, const float* __restrict__ ie_,
                                    const unsigned short* __restrict__ h1,
                                    const unsigned short* __restrict__ h2,
                                    const unsigned short* __restrict__ h3,
                                    const int* __restrict__ uid, const int* __restrict__ iid,
                                    unsigned short* __restrict__ ue1b,
                                    unsigned short* __restrict__ ie1b, int B) {
    int gid = blockIdx.x * 256 + threadIdx.x;
    int t = gid >> 6;
    int lane = gid & 63;
    if (t >= 2 * B) return;
    bool user = (t < B);
    int r = user ? t : (t - B);
    int grow = user ? uid[r] : (USER_NUM + iid[r]);
    size_t idx = (size_t)grow * D + lane;
    float x = emb_at(ue_, ie_, grow, lane) + bf2f(h1[idx]) + bf2f(h2[idx]) + bf2f(h3[idx]);
    float s = x * x;
    #pragma unroll
    for (int o = 32; o; o >>= 1) s += __shfl_xor(s, o);
    float y = x / fmaxf(sqrtf(s), 1e-12f);
    (user ? ue1b : ie1b)[(size_t)r * D + lane] = f2bf(y);
}

// ---------------- full-row sum of 4 layers + l2-normalize -> h4 (bf16)
__global__ void sum_norm_all_kernel(const float* __restrict__ ue_, const float* __restrict__ ie_,
                                    const unsigned short* __restrict__ h1,
                                    const unsigned short* __restrict__ h2,
                                    const unsigned short* __restrict__ h3,
                                    unsigned short* __restrict__ out) {
    int gid = blockIdx.x * 256 + threadIdx.x;
    int row = gid >> 6;
    int lane = gid & 63;
    if (row >= NN) return;
    size_t idx = (size_t)row * D + lane;
    float x = emb_at(ue_, ie_, row, lane) + bf2f(h1[idx]) + bf2f(h2[idx]) + bf2f(h3[idx]);
    float s = x * x;
    #pragma unroll
    for (int o = 32; o; o >>= 1) s += __shfl_xor(s, o);
    out[idx] = f2bf(x / fmaxf(sqrtf(s), 1e-12f));
}

// ---------------- big SSL via MFMA, XCD-locality grid
__global__ __launch_bounds__(256) void ssl_mfma_kernel(const unsigned short* __restrict__ Ab,
                                                       const unsigned short* __restrict__ Bb,
                                                       float* __restrict__ rowsum,
                                                       int M, int nc) {
    int bid = blockIdx.x;
    int xcd = bid & 7;
    int inner = bid >> 3;
    int rg = inner & (NRG - 1);
    int cgrp = inner >> 6;
    int colChunk = cgrp * 8 + xcd;
    if (colChunk >= nc) return;

    int wave = threadIdx.x >> 6;
    int lane = threadIdx.x & 63;
    int l15 = lane & 15;
    int lg  = lane >> 4;
    int rgbase = rg * 64;
    int chunkbase = colChunk * (128 * NCITER);

    bf16x8 afr[4][2];
    {
        const unsigned short* ab = Ab + (size_t)(rgbase + l15) * D + lg * 8;
        #pragma unroll
        for (int i = 0; i < 4; i++) {
            afr[i][0] = *(const bf16x8*)(ab + (size_t)i * 16 * D);
            afr[i][1] = *(const bf16x8*)(ab + (size_t)i * 16 * D + 32);
        }
    }

    float rowacc[4][4];
    #pragma unroll
    for (int i = 0; i < 4; i++)
        #pragma unroll
        for (int r = 0; r < 4; r++) rowacc[i][r] = 0.f;

    for (int it = 0; it < NCITER; it++) {
        int cb = chunkbase + it * 128 + wave * 32;
        bf16x8 bfr[2][2];
        bool val[2];
        #pragma unroll
        for (int cf = 0; cf < 2; cf++) {
            int col = cb + cf * 16 + l15;
            val[cf] = (col < M);
            int cc = val[cf] ? col : (M - 1);
            const unsigned short* bp = Bb + (size_t)cc * D + lg * 8;
            bfr[cf][0] = *(const bf16x8*)(bp);
            bfr[cf][1] = *(const bf16x8*)(bp + 32);
        }

        f32x4 acc[4][2];
        #pragma unroll
        for (int i = 0; i < 4; i++)
            #pragma unroll
            for (int cf = 0; cf < 2; cf++)
                acc[i][cf] = (f32x4){0.f, 0.f, 0.f, 0.f};

        #pragma unroll
        for (int i = 0; i < 4; i++) {
            #pragma unroll
            for (int cf = 0; cf < 2; cf++) {
                acc[i][cf] = __builtin_amdgcn_mfma_f32_16x16x32_bf16(afr[i][0], bfr[cf][0], acc[i][cf], 0, 0, 0);
                acc[i][cf] = __builtin_amdgcn_mfma_f32_16x16x32_bf16(afr[i][1], bfr[cf][1], acc[i][cf], 0, 0, 0);
            }
        }

        #pragma unroll
        for (int i = 0; i < 4; i++) {
            #pragma unroll
            for (int r = 0; r < 4; r++) {
                float e0 = val[0] ? __expf(TAU_INV * acc[i][0][r]) : 0.f;
                float e1 = val[1] ? __expf(TAU_INV * acc[i][1][r]) : 0.f;
                rowacc[i][r] += e0 + e1;
            }
        }
    }

    #pragma unroll
    for (int i = 0; i < 4; i++) {
        #pragma unroll
        for (int r = 0; r < 4; r++) {
            float s = rowacc[i][r];
            s += __shfl_xor(s, 1);
            s += __shfl_xor(s, 2);
            s += __shfl_xor(s, 4);
            s += __shfl_xor(s, 8);
            if (l15 == 0) atomicAdd(&rowsum[rgbase + i * 16 + lg * 4 + r], s);
        }
    }
}

// ---------------- SSL finalize (A2 in bf16 = h4)
__global__ void ssl_fin_kernel(const unsigned short* __restrict__ ue1b,
                               const unsigned short* __restrict__ ie1b,
                               const unsigned short* __restrict__ A2b,
                               const int* __restrict__ uid, const int* __restrict__ iid,
                               const float* __restrict__ rsU, const float* __restrict__ rsI,
                               float* __restrict__ scal, int B) {
    int gid = blockIdx.x * 256 + threadIdx.x;
    int t = gid >> 6;
    int lane = gid & 63;
    if (t >= 2 * B) return;
    bool user = (t < B);
    int r = user ? t : (t - B);
    const unsigned short* a = (user ? ue1b : ie1b) + (size_t)r * D;
    size_t brow = user ? (size_t)uid[r] * D : (size_t)(USER_NUM + iid[r]) * D;
    float p = bf2f(a[lane]) * bf2f(A2b[brow + lane]);
    #pragma unroll
    for (int o = 32; o; o >>= 1) p += __shfl_xor(p, o);
    if (lane == 0) {
        float contrib = logf((user ? rsU : rsI)[r]) - p * TAU_INV;
        atomicAdd(&scal[user ? 2 : 3], contrib);
    }
}

// ---------------- final scalar
__global__ void final_kernel(const float* __restrict__ scal, float* __restrict__ out, int B) {
    if (threadIdx.x == 0 && blockIdx.x == 0) {
        float invB = 1.0f / (float)B;
        float bpr_loss = scal[0] * invB + LMBD * scal[1] * invB;
        float ssl_loss = (scal[2] + scal[3]) * 0.1f;
        out[0] = bpr_loss + ssl_loss;
    }
}

extern "C" void kernel_launch(void* const* d_in, const int* in_sizes, int n_in,
                              void* d_out, int out_size, void* d_ws, size_t ws_size,
                              hipStream_t stream) {
    const float* user_emb = (const float*)d_in[0];
    const float* item_emb = (const float*)d_in[1];
    const int*   src  = (const int*)d_in[2];
    const int*   dst  = (const int*)d_in[3];
    const float* w    = (const float*)d_in[4];
    const int*   src1 = (const int*)d_in[5];
    const int*   dst1 = (const int*)d_in[6];
    const float* w1   = (const float*)d_in[7];
    const int*   src2 = (const int*)d_in[8];
    const int*   dst2 = (const int*)d_in[9];
    const float* w2   = (const float*)d_in[10];
    const int* user_id = (const int*)d_in[11];
    const int* item_id = (const int*)d_in[12];
    const int* neg_id  = (const int*)d_in[13];
    int E0 = in_sizes[2];
    int E1 = in_sizes[5];
    int E2 = in_sizes[8];
    int B  = in_sizes[11];
    int ET = E0 + E1 + E2;

    size_t nd = (size_t)NN * D;
    unsigned short* h0 = (unsigned short*)d_ws;   // bf16 layer buffers
    unsigned short* h1 = h0 + nd;
    unsigned short* h2 = h1 + nd;
    unsigned short* h3 = h2 + nd;
    unsigned short* h4 = h3 + nd;
    unsigned short* ue1b = h4 + nd;
    unsigned short* ie1b = ue1b + (size_t)B * D;
    float* rsU  = (float*)(ie1b + (size_t)B * D);
    float* rsI  = rsU + B;
    float* scal = rsI + B;                 // 8 floats
    int* degD3   = (int*)(scal + 8);       // 3*NN
    int* rowptr3 = degD3 + T3;             // 3*NN + 1
    int* cursor3 = rowptr3 + T3 + 1;       // 3*NN
    int* bsum3   = cursor3 + T3;           // up to 2048
    int2* perm3  = (int2*)(((uintptr_t)(bsum3 + 2048) + 15) & ~(uintptr_t)15);  // ET int2

    hipMemsetAsync(rsU, 0, (size_t)(2 * B + 8) * sizeof(float), stream);
    hipMemsetAsync(degD3, 0, (size_t)T3 * sizeof(int), stream);

    int gridElem = (NN * D + 255) / 256;
    int gridRows = (NN * 64 + 255) / 256;
    int gridE8 = 8 * ((ET + EPB - 1) / EPB);

    // ---- embeddings -> h0 (once)
    init_kernel<<<gridElem, 256, 0, stream>>>(user_emb, item_emb, h0);

    // ---- fused XCD-pinned CSR build for all 3 graphs
    deg3p_kernel<<<gridE8, 256, 0, stream>>>(dst, dst1, dst2, degD3, E0, E1, E2, ET);
    scan_reduce_kernel<<<NBLK3, 256, 0, stream>>>(degD3, bsum3);
    scan_mid_kernel<<<1, 1024, 0, stream>>>(bsum3, rowptr3 + T3, NBLK3);
    scan_final_kernel<<<NBLK3, 256, 0, stream>>>(degD3, bsum3, rowptr3, cursor3);
    fill3p_kernel<<<gridE8, 256, 0, stream>>>(src, dst, w, src1, dst1, w1, src2, dst2, w2,
                                              cursor3, perm3, E0, E1, E2, ET);

    unsigned short* hs[5] = {h0, h1, h2, h3, h4};
    auto propagate = [&](int g, int layers) {
        const int* rp = rowptr3 + (size_t)g * NN;
        for (int l = 1; l <= layers; l++) {
            gather_kernel<<<gridRows, 256, 0, stream>>>(hs[l - 1], rp, perm3, hs[l]);
        }
    };

    // main graph: 4 layers -> BPR (sum-on-the-fly over sampled rows)
    propagate(0, 4);
    bpr_kernel<<<(B * 64) / 256, 256, 0, stream>>>(user_emb, item_emb, h1, h2, h3, h4,
                                                   user_id, item_id, neg_id, scal, B);

    // ssl graph 1: 3 layers -> normalized sampled rows (bf16)
    propagate(1, 3);
    extract_norm_kernel<<<(2 * B * 64) / 256, 256, 0, stream>>>(user_emb, item_emb, h1, h2, h3,
                                                                user_id, item_id, ue1b, ie1b, B);

    // ssl graph 2: 3 layers -> full normalized sum into h4 (bf16)
    propagate(2, 3);
    sum_norm_all_kernel<<<gridRows, 256, 0, stream>>>(user_emb, item_emb, h1, h2, h3, h4);

    // big SSL terms via MFMA (XCD-locality 1-D grid), B-matrix = h4
    {
        int ncU = (USER_NUM + 128 * NCITER - 1) / (128 * NCITER);
        int gu = 8 * NRG * ((ncU + 7) / 8);
        ssl_mfma_kernel<<<gu, 256, 0, stream>>>(ue1b, h4, rsU, USER_NUM, ncU);
        int ncI = (ITEM_NUM + 128 * NCITER - 1) / (128 * NCITER);
        int gi = 8 * NRG * ((ncI + 7) / 8);
        ssl_mfma_kernel<<<gi, 256, 0, stream>>>(ie1b, h4 + (size_t)USER_NUM * D, rsI, ITEM_NUM, ncI);
    }

    ssl_fin_kernel<<<(2 * B * 64) / 256, 256, 0, stream>>>(ue1b, ie1b, h4, user_id, item_id,
                                                           rsU, rsI, scal, B);
    final_kernel<<<1, 64, 0, stream>>>(scal, (float*)d_out, B);
}